// Round 7
// baseline (113.943 us; speedup 1.0000x reference)
//
#include <hip/hip_runtime.h>

#define D_MODEL 256
#define LN_EPS 1e-5f

typedef float f4 __attribute__((ext_vector_type(4)));

// ---------------------------------------------------------------------------
// Single fused kernel. Each wave owns a contiguous 64-row chunk (64 = SC tile,
// so fU/fB are per-wave constants). Per row: x[d] = a0*re + a1*im + a2*fS + w,
// where w(d) = fB*ws + fU*wu + (bc+bs+bu+bf) folds the wave constants.
// LayerNorm mean/var come from the 4x4 Gram of (a0,a1,a2,w) + the 4 means,
// computed per-wave with ONE 14-value butterfly (no LDS, no second kernel).
// Main loop has no vector loads (CSI via uniform s_load path).
// R7 A/B: plain (L2-allocating) stores instead of nontemporal — the harness
// fill kernels sustain 6.7-6.9 TB/s with plain stores on this same buffer.
// ---------------------------------------------------------------------------
__global__ __launch_bounds__(256) void csi_encoder_kernel(
    const float* __restrict__ csi_real,
    const float* __restrict__ csi_imag,
    const float* __restrict__ w_c,
    const float* __restrict__ b_c,
    const float* __restrict__ w_s,
    const float* __restrict__ b_s,
    const float* __restrict__ w_u,
    const float* __restrict__ b_u,
    const float* __restrict__ w_f,
    const float* __restrict__ b_f,
    const float* __restrict__ ln_gamma,
    const float* __restrict__ ln_beta,
    float* __restrict__ out)
{
    const int lane = threadIdx.x & 63;
    const int waveId = blockIdx.x * 4 + (threadIdx.x >> 6);   // 0..8191
    const int rbase = __builtin_amdgcn_readfirstlane(waveId * 64);

    const int s0i = rbase & 511;                 // starting subcarrier index
    const float fU = (float)((rbase >> 9) & 3);
    const float fB = (float)((rbase >> 11) & 63);

    // Per-lane (per-d) constants for d = d0..d0+3.
    const int d0 = lane * 4;
    float a0[4], a1[4], a2[4], wv[4], gv[4], bv[4];
#pragma unroll
    for (int j = 0; j < 4; ++j) {
        const int d = d0 + j;
        a0[j] = w_c[d * 2 + 0];
        a1[j] = w_c[d * 2 + 1];
        a2[j] = w_f[d];
        const float bsum = b_c[d] + b_s[d] + b_u[d] + b_f[d];
        wv[j] = fmaf(fB, w_s[d], fmaf(fU, w_u[d], bsum));
        gv[j] = ln_gamma[d];
        bv[j] = ln_beta[d];
    }

    // 14 sums over d: 4x4 Gram (10) + means (4) of h = (a0, a1, a2, w).
    float p[14];
#pragma unroll
    for (int i = 0; i < 14; ++i) p[i] = 0.0f;
#pragma unroll
    for (int j = 0; j < 4; ++j) {
        p[0]  = fmaf(a0[j], a0[j], p[0]);
        p[1]  = fmaf(a1[j], a1[j], p[1]);
        p[2]  = fmaf(a2[j], a2[j], p[2]);
        p[3]  = fmaf(wv[j], wv[j], p[3]);
        p[4]  = fmaf(a0[j], a1[j], p[4]);
        p[5]  = fmaf(a0[j], a2[j], p[5]);
        p[6]  = fmaf(a0[j], wv[j], p[6]);
        p[7]  = fmaf(a1[j], a2[j], p[7]);
        p[8]  = fmaf(a1[j], wv[j], p[8]);
        p[9]  = fmaf(a2[j], wv[j], p[9]);
        p[10] += a0[j];
        p[11] += a1[j];
        p[12] += a2[j];
        p[13] += wv[j];
    }
#pragma unroll
    for (int off = 32; off >= 1; off >>= 1) {
#pragma unroll
        for (int i = 0; i < 14; ++i) p[i] += __shfl_xor(p[i], off, 64);
    }

    const float inv = 1.0f / 256.0f;
    const float E00 = p[0] * inv,  E11 = p[1] * inv,  E22 = p[2] * inv;
    const float E33 = p[3] * inv;
    const float F01 = 2.0f * p[4] * inv, F02 = 2.0f * p[5] * inv;
    const float F03 = 2.0f * p[6] * inv, F12 = 2.0f * p[7] * inv;
    const float F13 = 2.0f * p[8] * inv, F23 = 2.0f * p[9] * inv;
    const float M0 = p[10] * inv, M1 = p[11] * inv;
    const float M2 = p[12] * inv, M3 = p[13] * inv;

    // Uniform base pointers for this wave's chunk.
    const float* __restrict__ cr = csi_real + rbase;
    const float* __restrict__ ci = csi_imag + rbase;
    float* __restrict__ op = out + (size_t)rbase * D_MODEL + d0;

#pragma unroll 8
    for (int j = 0; j < 64; ++j) {
        const float re = cr[j];              // uniform -> s_load (lgkmcnt)
        const float im = ci[j];              // uniform -> s_load (lgkmcnt)
        const float fS = (float)(s0i + j);

        const float mu = fmaf(M0, re, fmaf(M1, im, fmaf(M2, fS, M3)));
        const float ms = fmaf(re, fmaf(E00, re, fmaf(F01, im, fmaf(F02, fS, F03))),
                         fmaf(im, fmaf(E11, im, fmaf(F12, fS, F13)),
                         fmaf(fS, fmaf(E22, fS, F23), E33)));
        const float var  = fmaf(-mu, mu, ms);
        const float rstd = rsqrtf(var + LN_EPS);

        f4 o;
#pragma unroll
        for (int k = 0; k < 4; ++k) {
            const float t = fmaf(re, a0[k], fmaf(im, a1[k], fmaf(fS, a2[k], wv[k])));
            o[k] = fmaf((t - mu) * rstd, gv[k], bv[k]);
        }
        *reinterpret_cast<f4*>(op + (size_t)j * D_MODEL) = o;   // plain store (A/B vs NT)
    }
}

extern "C" void kernel_launch(void* const* d_in, const int* in_sizes, int n_in,
                              void* d_out, int out_size, void* d_ws, size_t ws_size,
                              hipStream_t stream) {
    const float* csi_real = (const float*)d_in[0];
    const float* csi_imag = (const float*)d_in[1];
    const float* w_c      = (const float*)d_in[2];
    const float* b_c      = (const float*)d_in[3];
    const float* w_s      = (const float*)d_in[4];
    const float* b_s      = (const float*)d_in[5];
    const float* w_u      = (const float*)d_in[6];
    const float* b_u      = (const float*)d_in[7];
    const float* w_f      = (const float*)d_in[8];
    const float* b_f      = (const float*)d_in[9];
    const float* ln_gamma = (const float*)d_in[10];
    const float* ln_beta  = (const float*)d_in[11];
    float* out = (float*)d_out;

    // 2048 blocks x 4 waves = 8192 waves; each owns a contiguous 64-row chunk.
    csi_encoder_kernel<<<2048, 256, 0, stream>>>(
        csi_real, csi_imag, w_c, b_c, w_s, b_s, w_u, b_u, w_f, b_f,
        ln_gamma, ln_beta, out);
}

// Round 8
// 102.994 us; speedup vs baseline: 1.1063x; 1.1063x over previous
//
#include <hip/hip_runtime.h>

#define D_MODEL 256
#define LN_EPS 1e-5f

typedef float f4 __attribute__((ext_vector_type(4)));

// Force a wave-uniform float into an SGPR.
__device__ __forceinline__ float rfl(float x) {
    return __uint_as_float(__builtin_amdgcn_readfirstlane(__float_as_uint(x)));
}

// ---------------------------------------------------------------------------
// Single fused kernel. Each wave owns a contiguous 64-row chunk (64 = SC tile,
// so fU/fB are per-wave constants). Per row: x[d] = a0*re + a1*im + a2*fS + w,
// where w(d) = fB*ws + fU*wu + (bc+bs+bu+bf) folds the wave constants.
// LayerNorm mean/var from the 4x4 Gram of (a0,a1,a2,w) + 4 means (one
// 14-value butterfly per wave). Loop has no vector loads (CSI via s_load path)
// and nontemporal stores (R7 A/B: NT beats plain by 10%).
// R8 lever: __launch_bounds__(256,8) -> VGPR<=64 -> 32 waves/CU (was ~16).
// Gram constants moved to SGPRs (rfl) + unroll 4 to fit the budget.
// ---------------------------------------------------------------------------
__global__ __launch_bounds__(256, 8) void csi_encoder_kernel(
    const float* __restrict__ csi_real,
    const float* __restrict__ csi_imag,
    const float* __restrict__ w_c,
    const float* __restrict__ b_c,
    const float* __restrict__ w_s,
    const float* __restrict__ b_s,
    const float* __restrict__ w_u,
    const float* __restrict__ b_u,
    const float* __restrict__ w_f,
    const float* __restrict__ b_f,
    const float* __restrict__ ln_gamma,
    const float* __restrict__ ln_beta,
    float* __restrict__ out)
{
    const int lane = threadIdx.x & 63;
    const int waveId = blockIdx.x * 4 + (threadIdx.x >> 6);   // 0..8191
    const int rbase = __builtin_amdgcn_readfirstlane(waveId * 64);

    const int s0i = rbase & 511;                 // starting subcarrier index
    const float fU = (float)((rbase >> 9) & 3);
    const float fB = (float)((rbase >> 11) & 63);

    // Per-lane (per-d) constants for d = d0..d0+3.  (24 VGPRs live)
    const int d0 = lane * 4;
    float a0[4], a1[4], a2[4], wv[4], gv[4], bv[4];
#pragma unroll
    for (int j = 0; j < 4; ++j) {
        const int d = d0 + j;
        a0[j] = w_c[d * 2 + 0];
        a1[j] = w_c[d * 2 + 1];
        a2[j] = w_f[d];
        const float bsum = b_c[d] + b_s[d] + b_u[d] + b_f[d];
        wv[j] = fmaf(fB, w_s[d], fmaf(fU, w_u[d], bsum));
        gv[j] = ln_gamma[d];
        bv[j] = ln_beta[d];
    }

    // 14 sums over d: 4x4 Gram (10) + means (4) of h = (a0, a1, a2, w).
    float p[14];
#pragma unroll
    for (int i = 0; i < 14; ++i) p[i] = 0.0f;
#pragma unroll
    for (int j = 0; j < 4; ++j) {
        p[0]  = fmaf(a0[j], a0[j], p[0]);
        p[1]  = fmaf(a1[j], a1[j], p[1]);
        p[2]  = fmaf(a2[j], a2[j], p[2]);
        p[3]  = fmaf(wv[j], wv[j], p[3]);
        p[4]  = fmaf(a0[j], a1[j], p[4]);
        p[5]  = fmaf(a0[j], a2[j], p[5]);
        p[6]  = fmaf(a0[j], wv[j], p[6]);
        p[7]  = fmaf(a1[j], a2[j], p[7]);
        p[8]  = fmaf(a1[j], wv[j], p[8]);
        p[9]  = fmaf(a2[j], wv[j], p[9]);
        p[10] += a0[j];
        p[11] += a1[j];
        p[12] += a2[j];
        p[13] += wv[j];
    }
#pragma unroll
    for (int off = 32; off >= 1; off >>= 1) {
#pragma unroll
        for (int i = 0; i < 14; ++i) p[i] += __shfl_xor(p[i], off, 64);
    }

    // Wave-uniform constants -> SGPRs (frees ~14 VGPRs; each FMA below uses
    // at most one SGPR operand, which gfx950 VALU permits).
    const float inv = 1.0f / 256.0f;
    const float E00 = rfl(p[0] * inv);
    const float E11 = rfl(p[1] * inv);
    const float E22 = rfl(p[2] * inv);
    const float E33 = rfl(p[3] * inv);
    const float F01 = rfl(2.0f * p[4] * inv);
    const float F02 = rfl(2.0f * p[5] * inv);
    const float F03 = rfl(2.0f * p[6] * inv);
    const float F12 = rfl(2.0f * p[7] * inv);
    const float F13 = rfl(2.0f * p[8] * inv);
    const float F23 = rfl(2.0f * p[9] * inv);
    const float M0  = rfl(p[10] * inv);
    const float M1  = rfl(p[11] * inv);
    const float M2  = rfl(p[12] * inv);
    const float M3  = rfl(p[13] * inv);

    // Uniform base pointers for this wave's chunk.
    const float* __restrict__ cr = csi_real + rbase;
    const float* __restrict__ ci = csi_imag + rbase;
    float* __restrict__ op = out + (size_t)rbase * D_MODEL + d0;

#pragma unroll 4
    for (int j = 0; j < 64; ++j) {
        const float re = cr[j];              // uniform -> s_load (lgkmcnt)
        const float im = ci[j];              // uniform -> s_load (lgkmcnt)
        const float fS = (float)(s0i + j);

        const float mu = fmaf(M0, re, fmaf(M1, im, fmaf(M2, fS, M3)));
        const float ms = fmaf(re, fmaf(E00, re, fmaf(F01, im, fmaf(F02, fS, F03))),
                         fmaf(im, fmaf(E11, im, fmaf(F12, fS, F13)),
                         fmaf(fS, fmaf(E22, fS, F23), E33)));
        const float var  = fmaf(-mu, mu, ms);
        const float rstd = rsqrtf(var + LN_EPS);

        f4 o;
#pragma unroll
        for (int k = 0; k < 4; ++k) {
            const float t = fmaf(re, a0[k], fmaf(im, a1[k], fmaf(fS, a2[k], wv[k])));
            o[k] = fmaf((t - mu) * rstd, gv[k], bv[k]);
        }
        __builtin_nontemporal_store(o, (f4*)(op + (size_t)j * D_MODEL));
    }
}

extern "C" void kernel_launch(void* const* d_in, const int* in_sizes, int n_in,
                              void* d_out, int out_size, void* d_ws, size_t ws_size,
                              hipStream_t stream) {
    const float* csi_real = (const float*)d_in[0];
    const float* csi_imag = (const float*)d_in[1];
    const float* w_c      = (const float*)d_in[2];
    const float* b_c      = (const float*)d_in[3];
    const float* w_s      = (const float*)d_in[4];
    const float* b_s      = (const float*)d_in[5];
    const float* w_u      = (const float*)d_in[6];
    const float* b_u      = (const float*)d_in[7];
    const float* w_f      = (const float*)d_in[8];
    const float* b_f      = (const float*)d_in[9];
    const float* ln_gamma = (const float*)d_in[10];
    const float* ln_beta  = (const float*)d_in[11];
    float* out = (float*)d_out;

    // 2048 blocks x 4 waves = 8192 waves; each owns a contiguous 64-row chunk.
    csi_encoder_kernel<<<2048, 256, 0, stream>>>(
        csi_real, csi_imag, w_c, b_c, w_s, b_s, w_u, b_u, w_f, b_f,
        ln_gamma, ln_beta, out);
}